// Round 7
// baseline (414.279 us; speedup 1.0000x reference)
//
#include <hip/hip_runtime.h>

#define N_NODES 10000
#define N_EDGES 320000
#define N_CAND  100000
#define HID     256
#define N_MP    3
#define N_ATYPE 100

static __device__ __forceinline__ float relu_f(float x) { return x > 0.f ? x : 0.f; }

// ---------------------------------------------------------------------------
// GEMM core: C tile (mb,nb) += A[M x 256] @ B[256 x 64 slice] over K range
// [kbase, kbase+klen). BM=64, BN=64, BK=32; 256 threads; 4x4 per thread.
// As stored transposed [k][m ^ ((k>>2)<<2)] -> conflict-free (verified R6).
// ---------------------------------------------------------------------------
static __device__ __forceinline__ void gemm_core(
    const float* __restrict__ A, const float* __restrict__ B,
    const float* __restrict__ bias, const float* __restrict__ scale,
    float* __restrict__ C, int M, int mb, int nb,
    int kbase, int klen, int doRelu)
{
    __shared__ float As[32][64];   // [k][m ^ ((k>>2)<<2)]
    __shared__ float Bs[32][64];   // [k][n]

    int tid = threadIdx.x;
    int tx = tid & 15;
    int ty = tid >> 4;

    float acc[4][4] = {};

    for (int k0 = kbase; k0 < kbase + klen; k0 += 32) {
        #pragma unroll
        for (int p = 0; p < 2; ++p) {
            int flat = p * 256 + tid;      // 0..511
            int row  = flat >> 3;          // 0..63 (m)
            int kc   = flat & 7;           // 0..7
            float4 av = make_float4(0.f, 0.f, 0.f, 0.f);
            if (mb + row < M)
                av = *(const float4*)(A + (size_t)(mb + row) * 256 + k0 + kc * 4);
            int sc = row ^ (kc << 2);
            As[kc * 4 + 0][sc] = av.x;
            As[kc * 4 + 1][sc] = av.y;
            As[kc * 4 + 2][sc] = av.z;
            As[kc * 4 + 3][sc] = av.w;
        }
        #pragma unroll
        for (int p = 0; p < 2; ++p) {
            int flat = p * 256 + tid;
            int row  = flat >> 4;          // 0..31
            int c    = flat & 15;
            *(float4*)(&Bs[row][c * 4]) =
                *(const float4*)(B + (size_t)(k0 + row) * 256 + nb + c * 4);
        }
        __syncthreads();

        #pragma unroll 16
        for (int k = 0; k < 32; ++k) {
            float4 a4 = *(const float4*)(&As[k][(ty * 4) ^ ((k >> 2) << 2)]);
            float4 b4 = *(const float4*)(&Bs[k][tx * 4]);
            float a[4] = {a4.x, a4.y, a4.z, a4.w};
            float b[4] = {b4.x, b4.y, b4.z, b4.w};
            #pragma unroll
            for (int i = 0; i < 4; ++i)
                #pragma unroll
                for (int j = 0; j < 4; ++j)
                    acc[i][j] = fmaf(a[i], b[j], acc[i][j]);
        }
        __syncthreads();
    }

    float bvv[4] = {0.f, 0.f, 0.f, 0.f};
    if (bias) {
        float4 bv = *(const float4*)(bias + nb + tx * 4);
        bvv[0] = bv.x; bvv[1] = bv.y; bvv[2] = bv.z; bvv[3] = bv.w;
    }
    #pragma unroll
    for (int i = 0; i < 4; ++i) {
        int row = mb + ty * 4 + i;
        if (row >= M) continue;
        float sc = scale ? scale[row] : 1.0f;
        float r[4];
        #pragma unroll
        for (int j = 0; j < 4; ++j) {
            r[j] = acc[i][j] + bvv[j];
            if (doRelu) r[j] = relu_f(r[j]);
            r[j] *= sc;
        }
        *(float4*)(C + (size_t)row * 256 + nb + tx * 4) =
            make_float4(r[0], r[1], r[2], r[3]);
    }
}

// generic 2D (E0 = atom_embed @ atom_W + atom_b)
__global__ __launch_bounds__(256) void k_gemm(
    const float* __restrict__ A, const float* __restrict__ B,
    const float* __restrict__ bias, float* __restrict__ C,
    int M, int doRelu)
{
    gemm_core(A, B, bias, nullptr, C, M, blockIdx.x * 64, blockIdx.y * 64,
              0, 256, doRelu);
}

// conv GEMM split-K2. Index space: l(8) x ks(2) x y(4) x g(20) = 1280 blocks.
__global__ __launch_bounds__(256) void k_gemm_conv(
    const float* __restrict__ A, const float* __restrict__ B,
    float* __restrict__ C0, float* __restrict__ C1, int M)
{
    int bid = blockIdx.x;
    int l = bid & 7;
    int r = bid >> 3;          // 0..159
    int ks = r & 1;
    int y  = (r >> 1) & 3;
    int g  = r >> 3;           // 0..19
    int x  = g * 8 + l;
    if (x * 64 >= M) return;
    float* C = ks ? C1 : C0;
    gemm_core(A, B, nullptr, nullptr, C, M, x * 64, y * 64, ks * 128, 128, 0);
}

// combine: C0 = act(C0 + C1 + bias) * scale
__global__ __launch_bounds__(256) void k_combine(
    float* __restrict__ C0, const float* __restrict__ C1,
    const float* __restrict__ bias, const float* __restrict__ scale)
{
    int i = blockIdx.x * 256 + threadIdx.x;
    if (i >= N_NODES * 64) return;
    int row  = i >> 6;
    int col4 = i & 63;
    float4 a = ((const float4*)C0)[i];
    float4 b = ((const float4*)C1)[i];
    float4 bv = ((const float4*)bias)[col4];
    float sc = scale ? scale[row] : 1.0f;
    float4 r;
    r.x = relu_f(a.x + b.x + bv.x) * sc;
    r.y = relu_f(a.y + b.y + bv.y) * sc;
    r.z = relu_f(a.z + b.z + bv.z) * sc;
    r.w = relu_f(a.w + b.w + bv.w) * sc;
    ((float4*)C0)[i] = r;
}

// merged P/Q projection, split-K2.
// Index space: l(8) x ks(2) x y(4) x half(2) x g(20) = 2560 blocks.
// half: 0 -> P (W1 rows 0..255), 1 -> Q (W1 rows 256..511)
// ks:   K-range [ks*128, ks*128+128) -> partial buffers {P0,P1,Q0,Q1}
__global__ __launch_bounds__(256) void k_gemm_pq(
    const float* __restrict__ A, const float* __restrict__ W1,
    float* __restrict__ P0, float* __restrict__ P1,
    float* __restrict__ Q0, float* __restrict__ Q1, int M)
{
    int bid = blockIdx.x;
    int l = bid & 7;
    int r = bid >> 3;          // 0..319
    int ks   = r & 1;
    int y    = (r >> 1) & 3;
    int half = (r >> 3) & 1;
    int g    = r >> 4;         // 0..19
    int x    = g * 8 + l;
    if (x * 64 >= M) return;
    const float* B = W1 + (size_t)half * 256 * 256;
    float* C = half ? (ks ? Q1 : Q0) : (ks ? P1 : P0);
    gemm_core(A, B, nullptr, nullptr, C, M, x * 64, y * 64, ks * 128, 128, 0);
}

// ---------------------------------------------------------------------------
__global__ void k_hist(const int* __restrict__ ei,
                       int* __restrict__ dout, int* __restrict__ din)
{
    int e = blockIdx.x * blockDim.x + threadIdx.x;
    if (e >= N_EDGES) return;
    atomicAdd(&dout[ei[e]], 1);
    atomicAdd(&din[ei[N_EDGES + e]], 1);
}

__global__ void k_norm(const int* __restrict__ dout, const int* __restrict__ din,
                       float* __restrict__ ns, float* __restrict__ nd)
{
    int i = blockIdx.x * blockDim.x + threadIdx.x;
    if (i >= N_NODES) return;
    int o = dout[i], in = din[i];
    ns[i] = (o  > 0) ? (1.0f / sqrtf((float)o))  : 0.f;
    nd[i] = (in > 0) ? (1.0f / sqrtf((float)in)) : 0.f;
}

// h0[node][:] = E0[atom_types[node]][:] * ns[node]
__global__ __launch_bounds__(256) void k_h0(const int* __restrict__ types,
                                            const float* __restrict__ E0,
                                            const float* __restrict__ ns,
                                            float* __restrict__ h)
{
    int node = blockIdx.x * 4 + (threadIdx.x >> 6);
    int lane = threadIdx.x & 63;
    if (node >= N_NODES) return;
    int t = types[node];
    float s = ns[node];
    float4 v = ((const float4*)E0)[t * 64 + lane];
    v.x *= s; v.y *= s; v.z *= s; v.w *= s;
    ((float4*)h)[node * 64 + lane] = v;
}

__global__ __launch_bounds__(1024) void k_scan(const int* __restrict__ deg,
                                               int* __restrict__ off, int n)
{
    __shared__ int part[1024];
    int t = threadIdx.x;
    int chunk = (n + 1023) / 1024;
    int base = t * chunk;
    int s = 0;
    for (int i = 0; i < chunk; ++i) {
        int idx = base + i;
        if (idx < n) s += deg[idx];
    }
    part[t] = s;
    __syncthreads();
    for (int d = 1; d < 1024; d <<= 1) {
        int v = (t >= d) ? part[t - d] : 0;
        __syncthreads();
        part[t] += v;
        __syncthreads();
    }
    int run = (t == 0) ? 0 : part[t - 1];
    if (t == 0) off[0] = 0;
    for (int i = 0; i < chunk; ++i) {
        int idx = base + i;
        if (idx < n) { run += deg[idx]; off[idx + 1] = run; }
    }
}

__global__ void k_fill(const int* __restrict__ ei, const int* __restrict__ off,
                       int* __restrict__ cur, int* __restrict__ csr)
{
    int e = blockIdx.x * blockDim.x + threadIdx.x;
    if (e >= N_EDGES) return;
    int d = ei[N_EDGES + e];
    int p = off[d] + atomicAdd(&cur[d], 1);
    csr[p] = ei[e];
}

// ---------------------------------------------------------------------------
// Persistent column-chunked aggregation (XCD-local h stripes).
// 2048 blocks = 8 slots x 256; chunk c = slot>>1 pinned to XCD pair.
// 2048 waves per chunk stride the 10000 nodes (~5 nodes/wave).
// ---------------------------------------------------------------------------
__global__ __launch_bounds__(256) void k_agg(
    const float* __restrict__ h, const float* __restrict__ nd,
    const int* __restrict__ off, const int* __restrict__ csr,
    float* __restrict__ out)
{
    int bid  = blockIdx.x;
    int slot = bid & 7;
    int c    = slot >> 1;
    int p    = ((bid >> 3) << 1) | (slot & 1);   // 0..511 within chunk
    int wave = threadIdx.x >> 6;
    int lane = threadIdx.x & 63;
    int wi   = p * 4 + wave;                     // 0..2047
    int col  = c * 64 + lane;

    for (int node = wi; node < N_NODES; node += 2048) {
        int s0 = off[node], s1 = off[node + 1];
        float acc0 = 0.f, acc1 = 0.f, acc2 = 0.f, acc3 = 0.f;
        int e = s0;
        for (; e + 4 <= s1; e += 4) {
            int i0 = csr[e], i1 = csr[e + 1], i2 = csr[e + 2], i3 = csr[e + 3];
            float v0 = h[(size_t)i0 * 256 + col];
            float v1 = h[(size_t)i1 * 256 + col];
            float v2 = h[(size_t)i2 * 256 + col];
            float v3 = h[(size_t)i3 * 256 + col];
            acc0 += v0; acc1 += v1; acc2 += v2; acc3 += v3;
        }
        for (; e < s1; ++e)
            acc0 += h[(size_t)csr[e] * 256 + col];
        out[(size_t)node * 256 + col] = (acc0 + acc1 + acc2 + acc3) * nd[node];
    }
}

// ---------------------------------------------------------------------------
// Scoring: 8 chunks x 32 cols, chunk = bid&7 -> XCD-local stripes.
// Sums the 4 split-K partials (P0+P1, Q0+Q1) inline.
// ---------------------------------------------------------------------------
__global__ __launch_bounds__(256) void k_score_part(
    const int* __restrict__ cand,
    const float* __restrict__ P0, const float* __restrict__ P1,
    const float* __restrict__ Q0, const float* __restrict__ Q1,
    const float* __restrict__ b1, const float* __restrict__ W2,
    float* __restrict__ part)
{
    int bid = blockIdx.x;
    int c   = bid & 7;
    int grp = bid >> 3;
    int cd  = grp * 256 + threadIdx.x;
    if (cd >= N_CAND) return;

    int u = cand[2 * cd];
    int v = cand[2 * cd + 1];
    const float4* P04 = (const float4*)P0;
    const float4* P14 = (const float4*)P1;
    const float4* Q04 = (const float4*)Q0;
    const float4* Q14 = (const float4*)Q1;
    const float4* B4  = (const float4*)b1;
    const float4* W4  = (const float4*)W2;
    size_t pb = (size_t)u * 64 + c * 8;
    size_t qb = (size_t)v * 64 + c * 8;

    float acc = 0.f;
    #pragma unroll
    for (int i = 0; i < 8; ++i) {
        float4 pa = P04[pb + i];
        float4 pbv = P14[pb + i];
        float4 qa = Q04[qb + i];
        float4 qbv = Q14[qb + i];
        float4 b = B4[c * 8 + i];
        float4 w = W4[c * 8 + i];
        acc = fmaf(relu_f(pa.x + pbv.x + qa.x + qbv.x + b.x), w.x, acc);
        acc = fmaf(relu_f(pa.y + pbv.y + qa.y + qbv.y + b.y), w.y, acc);
        acc = fmaf(relu_f(pa.z + pbv.z + qa.z + qbv.z + b.z), w.z, acc);
        acc = fmaf(relu_f(pa.w + pbv.w + qa.w + qbv.w + b.w), w.w, acc);
    }
    part[(size_t)c * N_CAND + cd] = acc;
}

__global__ void k_sred(const float* __restrict__ part,
                       const float* __restrict__ b2, float* __restrict__ out)
{
    int i = blockIdx.x * 256 + threadIdx.x;
    if (i >= N_CAND) return;
    float s = b2[0];
    #pragma unroll
    for (int c = 0; c < 8; ++c) s += part[(size_t)c * N_CAND + i];
    out[i] = s;
}

// ---------------------------------------------------------------------------
extern "C" void kernel_launch(void* const* d_in, const int* in_sizes, int n_in,
                              void* d_out, int out_size, void* d_ws, size_t ws_size,
                              hipStream_t stream)
{
    const int*   atom_types = (const int*)d_in[0];
    const int*   edge_index = (const int*)d_in[2];
    const int*   candidates = (const int*)d_in[3];
    const float* atom_embed = (const float*)d_in[4];
    const float* atom_W     = (const float*)d_in[5];
    const float* atom_b     = (const float*)d_in[6];
    const float* conv_W     = (const float*)d_in[10];
    const float* conv_b     = (const float*)d_in[11];
    const float* s_W1       = (const float*)d_in[12];
    const float* s_b1       = (const float*)d_in[13];
    const float* s_W2       = (const float*)d_in[14];
    const float* s_b2       = (const float*)d_in[15];
    float* out = (float*)d_out;

    char* w = (char*)d_ws;
    size_t o = 0;
    auto alloc = [&](size_t bytes) {
        void* p = w + o;
        o += (bytes + 255) & ~(size_t)255;
        return p;
    };
    float* h0   = (float*)alloc((size_t)N_NODES * HID * 4);
    float* h1   = (float*)alloc((size_t)N_NODES * HID * 4);
    float* agg  = (float*)alloc((size_t)N_NODES * HID * 4);
    float* ctmp = (float*)alloc((size_t)N_NODES * HID * 4);
    float* q1b  = (float*)alloc((size_t)N_NODES * HID * 4);   // 4th pq partial
    float* E0   = (float*)alloc((size_t)N_ATYPE * HID * 4);
    float* part = (float*)alloc((size_t)8 * N_CAND * 4);
    int*   ints = (int*)alloc((size_t)3 * N_NODES * 4);
    float* ns   = (float*)alloc((size_t)N_NODES * 4);
    float* nd   = (float*)alloc((size_t)N_NODES * 4);
    int*   off  = (int*)alloc((size_t)(N_NODES + 1) * 4);
    int*   csr  = (int*)alloc((size_t)N_EDGES * 4);
    int* dego = ints;
    int* degi = ints + N_NODES;
    int* cur  = ints + 2 * N_NODES;

    hipMemsetAsync(ints, 0, (size_t)3 * N_NODES * 4, stream);

    // E0 = atom_embed @ atom_W + atom_b
    k_gemm<<<dim3(2, 4), 256, 0, stream>>>(atom_embed, atom_W, atom_b, E0, N_ATYPE, 0);

    k_hist<<<(N_EDGES + 255) / 256, 256, 0, stream>>>(edge_index, dego, degi);
    k_norm<<<(N_NODES + 255) / 256, 256, 0, stream>>>(dego, degi, ns, nd);
    k_h0<<<N_NODES / 4, 256, 0, stream>>>(atom_types, E0, ns, h0);
    k_scan<<<1, 1024, 0, stream>>>(degi, off, N_NODES);
    k_fill<<<(N_EDGES + 255) / 256, 256, 0, stream>>>(edge_index, off, cur, csr);

    const float* hc = h0;
    float* hn = h1;
    const int NF4 = N_NODES * 64;
    for (int i = 0; i < N_MP; ++i) {
        k_agg<<<2048, 256, 0, stream>>>(hc, nd, off, csr, agg);
        k_gemm_conv<<<1280, 256, 0, stream>>>(
            agg, conv_W + (size_t)i * HID * HID, hn, ctmp, N_NODES);
        const float* sc = (i < N_MP - 1) ? ns : nullptr;
        k_combine<<<(NF4 + 255) / 256, 256, 0, stream>>>(
            hn, ctmp, conv_b + (size_t)i * HID, sc);
        float* t = (float*)hc; hc = hn; hn = t;
    }
    // After 3 layers: hc == h1 (final h). Free: h0 (hn), agg, ctmp.
    float* P0 = agg;
    float* P1 = ctmp;
    float* Q0 = hn;     // == h0
    float* Q1 = q1b;
    k_gemm_pq<<<2560, 256, 0, stream>>>(hc, s_W1, P0, P1, Q0, Q1, N_NODES);

    k_score_part<<<3128, 256, 0, stream>>>(candidates, P0, P1, Q0, Q1,
                                           s_b1, s_W2, part);
    k_sred<<<(N_CAND + 255) / 256, 256, 0, stream>>>(part, s_b2, out);
}

// Round 8
// 370.537 us; speedup vs baseline: 1.1181x; 1.1181x over previous
//
#include <hip/hip_runtime.h>

#define N_NODES 10000
#define N_EDGES 320000
#define N_CAND  100000
#define HID     256
#define N_MP    3
#define N_ATYPE 100

static __device__ __forceinline__ float relu_f(float x) { return x > 0.f ? x : 0.f; }

// ---------------------------------------------------------------------------
// GEMM core: C tile (mb,nb) += A[M x 256] @ B[256 x 64 slice] over K range
// [kbase, kbase+klen). BM=64, BN=64, BK=32; 256 threads; 4x4 per thread.
// As stored transposed [k][m ^ ((k>>2)<<2)] -> conflict-free (verified R6).
// ---------------------------------------------------------------------------
static __device__ __forceinline__ void gemm_core(
    const float* __restrict__ A, const float* __restrict__ B,
    const float* __restrict__ bias, const float* __restrict__ scale,
    float* __restrict__ C, int M, int mb, int nb,
    int kbase, int klen, int doRelu)
{
    __shared__ float As[32][64];   // [k][m ^ ((k>>2)<<2)]
    __shared__ float Bs[32][64];   // [k][n]

    int tid = threadIdx.x;
    int tx = tid & 15;
    int ty = tid >> 4;

    float acc[4][4] = {};

    for (int k0 = kbase; k0 < kbase + klen; k0 += 32) {
        #pragma unroll
        for (int p = 0; p < 2; ++p) {
            int flat = p * 256 + tid;      // 0..511
            int row  = flat >> 3;          // 0..63 (m)
            int kc   = flat & 7;           // 0..7
            float4 av = make_float4(0.f, 0.f, 0.f, 0.f);
            if (mb + row < M)
                av = *(const float4*)(A + (size_t)(mb + row) * 256 + k0 + kc * 4);
            int sc = row ^ (kc << 2);
            As[kc * 4 + 0][sc] = av.x;
            As[kc * 4 + 1][sc] = av.y;
            As[kc * 4 + 2][sc] = av.z;
            As[kc * 4 + 3][sc] = av.w;
        }
        #pragma unroll
        for (int p = 0; p < 2; ++p) {
            int flat = p * 256 + tid;
            int row  = flat >> 4;          // 0..31
            int c    = flat & 15;
            *(float4*)(&Bs[row][c * 4]) =
                *(const float4*)(B + (size_t)(k0 + row) * 256 + nb + c * 4);
        }
        __syncthreads();

        #pragma unroll 16
        for (int k = 0; k < 32; ++k) {
            float4 a4 = *(const float4*)(&As[k][(ty * 4) ^ ((k >> 2) << 2)]);
            float4 b4 = *(const float4*)(&Bs[k][tx * 4]);
            float a[4] = {a4.x, a4.y, a4.z, a4.w};
            float b[4] = {b4.x, b4.y, b4.z, b4.w};
            #pragma unroll
            for (int i = 0; i < 4; ++i)
                #pragma unroll
                for (int j = 0; j < 4; ++j)
                    acc[i][j] = fmaf(a[i], b[j], acc[i][j]);
        }
        __syncthreads();
    }

    float bvv[4] = {0.f, 0.f, 0.f, 0.f};
    if (bias) {
        float4 bv = *(const float4*)(bias + nb + tx * 4);
        bvv[0] = bv.x; bvv[1] = bv.y; bvv[2] = bv.z; bvv[3] = bv.w;
    }
    #pragma unroll
    for (int i = 0; i < 4; ++i) {
        int row = mb + ty * 4 + i;
        if (row >= M) continue;
        float sc = scale ? scale[row] : 1.0f;
        float r[4];
        #pragma unroll
        for (int j = 0; j < 4; ++j) {
            r[j] = acc[i][j] + bvv[j];
            if (doRelu) r[j] = relu_f(r[j]);
            r[j] *= sc;
        }
        *(float4*)(C + (size_t)row * 256 + nb + tx * 4) =
            make_float4(r[0], r[1], r[2], r[3]);
    }
}

// generic 2D (E0 = atom_embed @ atom_W + atom_b)
__global__ __launch_bounds__(256) void k_gemm(
    const float* __restrict__ A, const float* __restrict__ B,
    const float* __restrict__ bias, float* __restrict__ C,
    int M, int doRelu)
{
    gemm_core(A, B, bias, nullptr, C, M, blockIdx.x * 64, blockIdx.y * 64,
              0, 256, doRelu);
}

// conv GEMM split-K2. Index space: l(8) x ks(2) x y(4) x g(20) = 1280 blocks.
__global__ __launch_bounds__(256) void k_gemm_conv(
    const float* __restrict__ A, const float* __restrict__ B,
    float* __restrict__ C0, float* __restrict__ C1, int M)
{
    int bid = blockIdx.x;
    int l = bid & 7;
    int r = bid >> 3;          // 0..159
    int ks = r & 1;
    int y  = (r >> 1) & 3;
    int g  = r >> 3;           // 0..19
    int x  = g * 8 + l;
    if (x * 64 >= M) return;
    float* C = ks ? C1 : C0;
    gemm_core(A, B, nullptr, nullptr, C, M, x * 64, y * 64, ks * 128, 128, 0);
}

// combine: C0 = act(C0 + C1 + bias) * scale
__global__ __launch_bounds__(256) void k_combine(
    float* __restrict__ C0, const float* __restrict__ C1,
    const float* __restrict__ bias, const float* __restrict__ scale)
{
    int i = blockIdx.x * 256 + threadIdx.x;
    if (i >= N_NODES * 64) return;
    int row  = i >> 6;
    int col4 = i & 63;
    float4 a = ((const float4*)C0)[i];
    float4 b = ((const float4*)C1)[i];
    float4 bv = ((const float4*)bias)[col4];
    float sc = scale ? scale[row] : 1.0f;
    float4 r;
    r.x = relu_f(a.x + b.x + bv.x) * sc;
    r.y = relu_f(a.y + b.y + bv.y) * sc;
    r.z = relu_f(a.z + b.z + bv.z) * sc;
    r.w = relu_f(a.w + b.w + bv.w) * sc;
    ((float4*)C0)[i] = r;
}

// merged P/Q projection, split-K2.
// Index space: l(8) x ks(2) x y(4) x half(2) x g(20) = 2560 blocks.
__global__ __launch_bounds__(256) void k_gemm_pq(
    const float* __restrict__ A, const float* __restrict__ W1,
    float* __restrict__ P0, float* __restrict__ P1,
    float* __restrict__ Q0, float* __restrict__ Q1, int M)
{
    int bid = blockIdx.x;
    int l = bid & 7;
    int r = bid >> 3;          // 0..319
    int ks   = r & 1;
    int y    = (r >> 1) & 3;
    int half = (r >> 3) & 1;
    int g    = r >> 4;         // 0..19
    int x    = g * 8 + l;
    if (x * 64 >= M) return;
    const float* B = W1 + (size_t)half * 256 * 256;
    float* C = half ? (ks ? Q1 : Q0) : (ks ? P1 : P0);
    gemm_core(A, B, nullptr, nullptr, C, M, x * 64, y * 64, ks * 128, 128, 0);
}

// collapse pq partials: P0 += P1, Q0 += Q1 (streaming; keeps score L2-local)
__global__ __launch_bounds__(256) void k_pqsum(
    float* __restrict__ P0, const float* __restrict__ P1,
    float* __restrict__ Q0, const float* __restrict__ Q1)
{
    const int NF4 = N_NODES * 64;
    int i = blockIdx.x * 256 + threadIdx.x;
    if (i < NF4) {
        float4 a = ((const float4*)P0)[i];
        float4 b = ((const float4*)P1)[i];
        a.x += b.x; a.y += b.y; a.z += b.z; a.w += b.w;
        ((float4*)P0)[i] = a;
    } else if (i < 2 * NF4) {
        int j = i - NF4;
        float4 a = ((const float4*)Q0)[j];
        float4 b = ((const float4*)Q1)[j];
        a.x += b.x; a.y += b.y; a.z += b.z; a.w += b.w;
        ((float4*)Q0)[j] = a;
    }
}

// ---------------------------------------------------------------------------
__global__ void k_hist(const int* __restrict__ ei,
                       int* __restrict__ dout, int* __restrict__ din)
{
    int e = blockIdx.x * blockDim.x + threadIdx.x;
    if (e >= N_EDGES) return;
    atomicAdd(&dout[ei[e]], 1);
    atomicAdd(&din[ei[N_EDGES + e]], 1);
}

__global__ void k_norm(const int* __restrict__ dout, const int* __restrict__ din,
                       float* __restrict__ ns, float* __restrict__ nd)
{
    int i = blockIdx.x * blockDim.x + threadIdx.x;
    if (i >= N_NODES) return;
    int o = dout[i], in = din[i];
    ns[i] = (o  > 0) ? (1.0f / sqrtf((float)o))  : 0.f;
    nd[i] = (in > 0) ? (1.0f / sqrtf((float)in)) : 0.f;
}

// h0[node][:] = E0[atom_types[node]][:] * ns[node]
__global__ __launch_bounds__(256) void k_h0(const int* __restrict__ types,
                                            const float* __restrict__ E0,
                                            const float* __restrict__ ns,
                                            float* __restrict__ h)
{
    int node = blockIdx.x * 4 + (threadIdx.x >> 6);
    int lane = threadIdx.x & 63;
    if (node >= N_NODES) return;
    int t = types[node];
    float s = ns[node];
    float4 v = ((const float4*)E0)[t * 64 + lane];
    v.x *= s; v.y *= s; v.z *= s; v.w *= s;
    ((float4*)h)[node * 64 + lane] = v;
}

__global__ __launch_bounds__(1024) void k_scan(const int* __restrict__ deg,
                                               int* __restrict__ off, int n)
{
    __shared__ int part[1024];
    int t = threadIdx.x;
    int chunk = (n + 1023) / 1024;
    int base = t * chunk;
    int s = 0;
    for (int i = 0; i < chunk; ++i) {
        int idx = base + i;
        if (idx < n) s += deg[idx];
    }
    part[t] = s;
    __syncthreads();
    for (int d = 1; d < 1024; d <<= 1) {
        int v = (t >= d) ? part[t - d] : 0;
        __syncthreads();
        part[t] += v;
        __syncthreads();
    }
    int run = (t == 0) ? 0 : part[t - 1];
    if (t == 0) off[0] = 0;
    for (int i = 0; i < chunk; ++i) {
        int idx = base + i;
        if (idx < n) { run += deg[idx]; off[idx + 1] = run; }
    }
}

__global__ void k_fill(const int* __restrict__ ei, const int* __restrict__ off,
                       int* __restrict__ cur, int* __restrict__ csr)
{
    int e = blockIdx.x * blockDim.x + threadIdx.x;
    if (e >= N_EDGES) return;
    int d = ei[N_EDGES + e];
    int p = off[d] + atomicAdd(&cur[d], 1);
    csr[p] = ei[e];
}

// ---------------------------------------------------------------------------
// Persistent column-chunked aggregation (XCD-local h stripes).
// ---------------------------------------------------------------------------
__global__ __launch_bounds__(256) void k_agg(
    const float* __restrict__ h, const float* __restrict__ nd,
    const int* __restrict__ off, const int* __restrict__ csr,
    float* __restrict__ out)
{
    int bid  = blockIdx.x;
    int slot = bid & 7;
    int c    = slot >> 1;
    int p    = ((bid >> 3) << 1) | (slot & 1);   // 0..511 within chunk
    int wave = threadIdx.x >> 6;
    int lane = threadIdx.x & 63;
    int wi   = p * 4 + wave;                     // 0..2047
    int col  = c * 64 + lane;

    for (int node = wi; node < N_NODES; node += 2048) {
        int s0 = off[node], s1 = off[node + 1];
        float acc0 = 0.f, acc1 = 0.f, acc2 = 0.f, acc3 = 0.f;
        int e = s0;
        for (; e + 4 <= s1; e += 4) {
            int i0 = csr[e], i1 = csr[e + 1], i2 = csr[e + 2], i3 = csr[e + 3];
            float v0 = h[(size_t)i0 * 256 + col];
            float v1 = h[(size_t)i1 * 256 + col];
            float v2 = h[(size_t)i2 * 256 + col];
            float v3 = h[(size_t)i3 * 256 + col];
            acc0 += v0; acc1 += v1; acc2 += v2; acc3 += v3;
        }
        for (; e < s1; ++e)
            acc0 += h[(size_t)csr[e] * 256 + col];
        out[(size_t)node * 256 + col] = (acc0 + acc1 + acc2 + acc3) * nd[node];
    }
}

// ---------------------------------------------------------------------------
// Scoring: 8 chunks x 32 cols, chunk = bid&7 -> XCD-local P/Q stripes
// (2.56 MB per XCD -> L2-resident). One candidate per thread.
// ---------------------------------------------------------------------------
__global__ __launch_bounds__(256) void k_score_part(
    const int* __restrict__ cand, const float* __restrict__ P,
    const float* __restrict__ Q, const float* __restrict__ b1,
    const float* __restrict__ W2, float* __restrict__ part)
{
    int bid = blockIdx.x;
    int c   = bid & 7;
    int grp = bid >> 3;
    int cd  = grp * 256 + threadIdx.x;
    if (cd >= N_CAND) return;

    int u = cand[2 * cd];
    int v = cand[2 * cd + 1];
    const float4* P4 = (const float4*)P;
    const float4* Q4 = (const float4*)Q;
    const float4* B4 = (const float4*)b1;
    const float4* W4 = (const float4*)W2;
    size_t pb = (size_t)u * 64 + c * 8;
    size_t qb = (size_t)v * 64 + c * 8;

    float acc = 0.f;
    #pragma unroll
    for (int i = 0; i < 8; ++i) {
        float4 p = P4[pb + i];
        float4 q = Q4[qb + i];
        float4 b = B4[c * 8 + i];
        float4 w = W4[c * 8 + i];
        acc = fmaf(relu_f(p.x + q.x + b.x), w.x, acc);
        acc = fmaf(relu_f(p.y + q.y + b.y), w.y, acc);
        acc = fmaf(relu_f(p.z + q.z + b.z), w.z, acc);
        acc = fmaf(relu_f(p.w + q.w + b.w), w.w, acc);
    }
    part[(size_t)c * N_CAND + cd] = acc;
}

__global__ void k_sred(const float* __restrict__ part,
                       const float* __restrict__ b2, float* __restrict__ out)
{
    int i = blockIdx.x * 256 + threadIdx.x;
    if (i >= N_CAND) return;
    float s = b2[0];
    #pragma unroll
    for (int c = 0; c < 8; ++c) s += part[(size_t)c * N_CAND + i];
    out[i] = s;
}

// ---------------------------------------------------------------------------
extern "C" void kernel_launch(void* const* d_in, const int* in_sizes, int n_in,
                              void* d_out, int out_size, void* d_ws, size_t ws_size,
                              hipStream_t stream)
{
    const int*   atom_types = (const int*)d_in[0];
    const int*   edge_index = (const int*)d_in[2];
    const int*   candidates = (const int*)d_in[3];
    const float* atom_embed = (const float*)d_in[4];
    const float* atom_W     = (const float*)d_in[5];
    const float* atom_b     = (const float*)d_in[6];
    const float* conv_W     = (const float*)d_in[10];
    const float* conv_b     = (const float*)d_in[11];
    const float* s_W1       = (const float*)d_in[12];
    const float* s_b1       = (const float*)d_in[13];
    const float* s_W2       = (const float*)d_in[14];
    const float* s_b2       = (const float*)d_in[15];
    float* out = (float*)d_out;

    char* w = (char*)d_ws;
    size_t o = 0;
    auto alloc = [&](size_t bytes) {
        void* p = w + o;
        o += (bytes + 255) & ~(size_t)255;
        return p;
    };
    float* h0   = (float*)alloc((size_t)N_NODES * HID * 4);
    float* h1   = (float*)alloc((size_t)N_NODES * HID * 4);
    float* agg  = (float*)alloc((size_t)N_NODES * HID * 4);
    float* ctmp = (float*)alloc((size_t)N_NODES * HID * 4);
    float* q1b  = (float*)alloc((size_t)N_NODES * HID * 4);
    float* E0   = (float*)alloc((size_t)N_ATYPE * HID * 4);
    float* part = (float*)alloc((size_t)8 * N_CAND * 4);
    int*   ints = (int*)alloc((size_t)3 * N_NODES * 4);
    float* ns   = (float*)alloc((size_t)N_NODES * 4);
    float* nd   = (float*)alloc((size_t)N_NODES * 4);
    int*   off  = (int*)alloc((size_t)(N_NODES + 1) * 4);
    int*   csr  = (int*)alloc((size_t)N_EDGES * 4);
    int* dego = ints;
    int* degi = ints + N_NODES;
    int* cur  = ints + 2 * N_NODES;

    hipMemsetAsync(ints, 0, (size_t)3 * N_NODES * 4, stream);

    // E0 = atom_embed @ atom_W + atom_b
    k_gemm<<<dim3(2, 4), 256, 0, stream>>>(atom_embed, atom_W, atom_b, E0, N_ATYPE, 0);

    k_hist<<<(N_EDGES + 255) / 256, 256, 0, stream>>>(edge_index, dego, degi);
    k_norm<<<(N_NODES + 255) / 256, 256, 0, stream>>>(dego, degi, ns, nd);
    k_h0<<<N_NODES / 4, 256, 0, stream>>>(atom_types, E0, ns, h0);
    k_scan<<<1, 1024, 0, stream>>>(degi, off, N_NODES);
    k_fill<<<(N_EDGES + 255) / 256, 256, 0, stream>>>(edge_index, off, cur, csr);

    const float* hc = h0;
    float* hn = h1;
    const int NF4 = N_NODES * 64;
    for (int i = 0; i < N_MP; ++i) {
        k_agg<<<2048, 256, 0, stream>>>(hc, nd, off, csr, agg);
        k_gemm_conv<<<1280, 256, 0, stream>>>(
            agg, conv_W + (size_t)i * HID * HID, hn, ctmp, N_NODES);
        const float* sc = (i < N_MP - 1) ? ns : nullptr;
        k_combine<<<(NF4 + 255) / 256, 256, 0, stream>>>(
            hn, ctmp, conv_b + (size_t)i * HID, sc);
        float* t = (float*)hc; hc = hn; hn = t;
    }
    // After 3 layers: hc == h1. Free: h0 (hn), agg, ctmp, q1b.
    float* P0 = agg;
    float* P1 = ctmp;
    float* Q0 = hn;     // == h0
    float* Q1 = q1b;
    k_gemm_pq<<<2560, 256, 0, stream>>>(hc, s_W1, P0, P1, Q0, Q1, N_NODES);
    k_pqsum<<<(2 * NF4 + 255) / 256, 256, 0, stream>>>(P0, P1, Q0, Q1);

    k_score_part<<<3128, 256, 0, stream>>>(candidates, P0, Q0, s_b1, s_W2, part);
    k_sred<<<(N_CAND + 255) / 256, 256, 0, stream>>>(part, s_b2, out);
}

// Round 9
// 354.225 us; speedup vs baseline: 1.1695x; 1.0460x over previous
//
#include <hip/hip_runtime.h>

#define N_NODES 10000
#define N_EDGES 320000
#define N_CAND  100000
#define HID     256
#define N_MP    3
#define N_ATYPE 100

static __device__ __forceinline__ float relu_f(float x) { return x > 0.f ? x : 0.f; }

// ---------------------------------------------------------------------------
// GEMM core: C tile (mb,nb) += A[M x 256] @ B[256 x 64 slice] over K range
// [kbase, kbase+klen). BM=64, BN=64, BK=32; 256 threads; 4x4 per thread.
// As stored transposed [k][m ^ ((k>>2)<<2)] -> conflict-free (verified R6).
// ---------------------------------------------------------------------------
static __device__ __forceinline__ void gemm_core(
    const float* __restrict__ A, const float* __restrict__ B,
    const float* __restrict__ bias, const float* __restrict__ scale,
    float* __restrict__ C, int M, int mb, int nb,
    int kbase, int klen, int doRelu)
{
    __shared__ float As[32][64];   // [k][m ^ ((k>>2)<<2)]
    __shared__ float Bs[32][64];   // [k][n]

    int tid = threadIdx.x;
    int tx = tid & 15;
    int ty = tid >> 4;

    float acc[4][4] = {};

    for (int k0 = kbase; k0 < kbase + klen; k0 += 32) {
        #pragma unroll
        for (int p = 0; p < 2; ++p) {
            int flat = p * 256 + tid;      // 0..511
            int row  = flat >> 3;          // 0..63 (m)
            int kc   = flat & 7;           // 0..7
            float4 av = make_float4(0.f, 0.f, 0.f, 0.f);
            if (mb + row < M)
                av = *(const float4*)(A + (size_t)(mb + row) * 256 + k0 + kc * 4);
            int sc = row ^ (kc << 2);
            As[kc * 4 + 0][sc] = av.x;
            As[kc * 4 + 1][sc] = av.y;
            As[kc * 4 + 2][sc] = av.z;
            As[kc * 4 + 3][sc] = av.w;
        }
        #pragma unroll
        for (int p = 0; p < 2; ++p) {
            int flat = p * 256 + tid;
            int row  = flat >> 4;          // 0..31
            int c    = flat & 15;
            *(float4*)(&Bs[row][c * 4]) =
                *(const float4*)(B + (size_t)(k0 + row) * 256 + nb + c * 4);
        }
        __syncthreads();

        #pragma unroll 16
        for (int k = 0; k < 32; ++k) {
            float4 a4 = *(const float4*)(&As[k][(ty * 4) ^ ((k >> 2) << 2)]);
            float4 b4 = *(const float4*)(&Bs[k][tx * 4]);
            float a[4] = {a4.x, a4.y, a4.z, a4.w};
            float b[4] = {b4.x, b4.y, b4.z, b4.w};
            #pragma unroll
            for (int i = 0; i < 4; ++i)
                #pragma unroll
                for (int j = 0; j < 4; ++j)
                    acc[i][j] = fmaf(a[i], b[j], acc[i][j]);
        }
        __syncthreads();
    }

    float bvv[4] = {0.f, 0.f, 0.f, 0.f};
    if (bias) {
        float4 bv = *(const float4*)(bias + nb + tx * 4);
        bvv[0] = bv.x; bvv[1] = bv.y; bvv[2] = bv.z; bvv[3] = bv.w;
    }
    #pragma unroll
    for (int i = 0; i < 4; ++i) {
        int row = mb + ty * 4 + i;
        if (row >= M) continue;
        float sc = scale ? scale[row] : 1.0f;
        float r[4];
        #pragma unroll
        for (int j = 0; j < 4; ++j) {
            r[j] = acc[i][j] + bvv[j];
            if (doRelu) r[j] = relu_f(r[j]);
            r[j] *= sc;
        }
        *(float4*)(C + (size_t)row * 256 + nb + tx * 4) =
            make_float4(r[0], r[1], r[2], r[3]);
    }
}

// generic 2D (E0 = atom_embed @ atom_W + atom_b)
__global__ __launch_bounds__(256) void k_gemm(
    const float* __restrict__ A, const float* __restrict__ B,
    const float* __restrict__ bias, float* __restrict__ C,
    int M, int doRelu)
{
    gemm_core(A, B, bias, nullptr, C, M, blockIdx.x * 64, blockIdx.y * 64,
              0, 256, doRelu);
}

// conv GEMM split-K2. Index space: l(8) x ks(2) x y(4) x g(20) = 1280 blocks.
__global__ __launch_bounds__(256) void k_gemm_conv(
    const float* __restrict__ A, const float* __restrict__ B,
    float* __restrict__ C0, float* __restrict__ C1, int M)
{
    int bid = blockIdx.x;
    int l = bid & 7;
    int r = bid >> 3;          // 0..159
    int ks = r & 1;
    int y  = (r >> 1) & 3;
    int g  = r >> 3;           // 0..19
    int x  = g * 8 + l;
    if (x * 64 >= M) return;
    float* C = ks ? C1 : C0;
    gemm_core(A, B, nullptr, nullptr, C, M, x * 64, y * 64, ks * 128, 128, 0);
}

// combine: C0 = act(C0 + C1 + bias) * scale
__global__ __launch_bounds__(256) void k_combine(
    float* __restrict__ C0, const float* __restrict__ C1,
    const float* __restrict__ bias, const float* __restrict__ scale)
{
    int i = blockIdx.x * 256 + threadIdx.x;
    if (i >= N_NODES * 64) return;
    int row  = i >> 6;
    int col4 = i & 63;
    float4 a = ((const float4*)C0)[i];
    float4 b = ((const float4*)C1)[i];
    float4 bv = ((const float4*)bias)[col4];
    float sc = scale ? scale[row] : 1.0f;
    float4 r;
    r.x = relu_f(a.x + b.x + bv.x) * sc;
    r.y = relu_f(a.y + b.y + bv.y) * sc;
    r.z = relu_f(a.z + b.z + bv.z) * sc;
    r.w = relu_f(a.w + b.w + bv.w) * sc;
    ((float4*)C0)[i] = r;
}

// merged P/Q projection (R6 version: full K, 1280 blocks).
// Index space: l(8) x y(8) x g(20) = 1280 blocks.
__global__ __launch_bounds__(256) void k_gemm_pq(
    const float* __restrict__ A, const float* __restrict__ W1,
    float* __restrict__ P, float* __restrict__ Q, int M)
{
    int bid = blockIdx.x;
    int l = bid & 7;
    int r = bid >> 3;          // 0..159
    int y = r & 7;
    int g = r >> 3;            // 0..19
    int x = g * 8 + l;
    if (x * 64 >= M) return;
    int half = y >> 2;
    const float* B = W1 + (size_t)half * 256 * 256;
    float* C = half ? Q : P;
    gemm_core(A, B, nullptr, nullptr, C, M, x * 64, (y & 3) * 64, 0, 256, 0);
}

// ---------------------------------------------------------------------------
__global__ void k_hist(const int* __restrict__ ei,
                       int* __restrict__ dout, int* __restrict__ din)
{
    int e = blockIdx.x * blockDim.x + threadIdx.x;
    if (e >= N_EDGES) return;
    atomicAdd(&dout[ei[e]], 1);
    atomicAdd(&din[ei[N_EDGES + e]], 1);
}

__global__ void k_norm(const int* __restrict__ dout, const int* __restrict__ din,
                       float* __restrict__ ns, float* __restrict__ nd)
{
    int i = blockIdx.x * blockDim.x + threadIdx.x;
    if (i >= N_NODES) return;
    int o = dout[i], in = din[i];
    ns[i] = (o  > 0) ? (1.0f / sqrtf((float)o))  : 0.f;
    nd[i] = (in > 0) ? (1.0f / sqrtf((float)in)) : 0.f;
}

// h0[node][:] = E0[atom_types[node]][:] * ns[node]
__global__ __launch_bounds__(256) void k_h0(const int* __restrict__ types,
                                            const float* __restrict__ E0,
                                            const float* __restrict__ ns,
                                            float* __restrict__ h)
{
    int node = blockIdx.x * 4 + (threadIdx.x >> 6);
    int lane = threadIdx.x & 63;
    if (node >= N_NODES) return;
    int t = types[node];
    float s = ns[node];
    float4 v = ((const float4*)E0)[t * 64 + lane];
    v.x *= s; v.y *= s; v.z *= s; v.w *= s;
    ((float4*)h)[node * 64 + lane] = v;
}

__global__ __launch_bounds__(1024) void k_scan(const int* __restrict__ deg,
                                               int* __restrict__ off, int n)
{
    __shared__ int part[1024];
    int t = threadIdx.x;
    int chunk = (n + 1023) / 1024;
    int base = t * chunk;
    int s = 0;
    for (int i = 0; i < chunk; ++i) {
        int idx = base + i;
        if (idx < n) s += deg[idx];
    }
    part[t] = s;
    __syncthreads();
    for (int d = 1; d < 1024; d <<= 1) {
        int v = (t >= d) ? part[t - d] : 0;
        __syncthreads();
        part[t] += v;
        __syncthreads();
    }
    int run = (t == 0) ? 0 : part[t - 1];
    if (t == 0) off[0] = 0;
    for (int i = 0; i < chunk; ++i) {
        int idx = base + i;
        if (idx < n) { run += deg[idx]; off[idx + 1] = run; }
    }
}

__global__ void k_fill(const int* __restrict__ ei, const int* __restrict__ off,
                       int* __restrict__ cur, int* __restrict__ csr)
{
    int e = blockIdx.x * blockDim.x + threadIdx.x;
    if (e >= N_EDGES) return;
    int d = ei[N_EDGES + e];
    int p = off[d] + atomicAdd(&cur[d], 1);
    csr[p] = ei[e];
}

// ---------------------------------------------------------------------------
// Persistent column-chunked aggregation (XCD-local h stripes), unroll-8
// for memory-level parallelism (8 independent gather loads in flight).
// ---------------------------------------------------------------------------
__global__ __launch_bounds__(256) void k_agg(
    const float* __restrict__ h, const float* __restrict__ nd,
    const int* __restrict__ off, const int* __restrict__ csr,
    float* __restrict__ out)
{
    int bid  = blockIdx.x;
    int slot = bid & 7;
    int c    = slot >> 1;
    int p    = ((bid >> 3) << 1) | (slot & 1);   // 0..511 within chunk
    int wave = threadIdx.x >> 6;
    int lane = threadIdx.x & 63;
    int wi   = p * 4 + wave;                     // 0..2047
    int col  = c * 64 + lane;

    for (int node = wi; node < N_NODES; node += 2048) {
        int s0 = off[node], s1 = off[node + 1];
        float a0 = 0.f, a1 = 0.f, a2 = 0.f, a3 = 0.f;
        float a4 = 0.f, a5 = 0.f, a6 = 0.f, a7 = 0.f;
        int e = s0;
        for (; e + 8 <= s1; e += 8) {
            int i0 = csr[e],     i1 = csr[e + 1], i2 = csr[e + 2], i3 = csr[e + 3];
            int i4 = csr[e + 4], i5 = csr[e + 5], i6 = csr[e + 6], i7 = csr[e + 7];
            float v0 = h[(size_t)i0 * 256 + col];
            float v1 = h[(size_t)i1 * 256 + col];
            float v2 = h[(size_t)i2 * 256 + col];
            float v3 = h[(size_t)i3 * 256 + col];
            float v4 = h[(size_t)i4 * 256 + col];
            float v5 = h[(size_t)i5 * 256 + col];
            float v6 = h[(size_t)i6 * 256 + col];
            float v7 = h[(size_t)i7 * 256 + col];
            a0 += v0; a1 += v1; a2 += v2; a3 += v3;
            a4 += v4; a5 += v5; a6 += v6; a7 += v7;
        }
        for (; e < s1; ++e)
            a0 += h[(size_t)csr[e] * 256 + col];
        float s = ((a0 + a1) + (a2 + a3)) + ((a4 + a5) + (a6 + a7));
        out[(size_t)node * 256 + col] = s * nd[node];
    }
}

// ---------------------------------------------------------------------------
// Scoring: 8 chunks x 32 cols, chunk = bid&7 -> XCD-local P/Q stripes
// (2.56 MB per XCD -> L2-resident). One candidate per thread.
// All 16 gather loads issued before any FMA (static unroll -> registers).
// ---------------------------------------------------------------------------
__global__ __launch_bounds__(256) void k_score_part(
    const int* __restrict__ cand, const float* __restrict__ P,
    const float* __restrict__ Q, const float* __restrict__ b1,
    const float* __restrict__ W2, float* __restrict__ part)
{
    int bid = blockIdx.x;
    int c   = bid & 7;
    int grp = bid >> 3;
    int cd  = grp * 256 + threadIdx.x;
    if (cd >= N_CAND) return;

    int u = cand[2 * cd];
    int v = cand[2 * cd + 1];
    const float4* P4 = (const float4*)P;
    const float4* Q4 = (const float4*)Q;
    const float4* B4 = (const float4*)b1;
    const float4* W4 = (const float4*)W2;
    size_t pb = (size_t)u * 64 + c * 8;
    size_t qb = (size_t)v * 64 + c * 8;

    float4 p[8], q[8];
    #pragma unroll
    for (int i = 0; i < 8; ++i) p[i] = P4[pb + i];
    #pragma unroll
    for (int i = 0; i < 8; ++i) q[i] = Q4[qb + i];

    float acc = 0.f;
    #pragma unroll
    for (int i = 0; i < 8; ++i) {
        float4 b = B4[c * 8 + i];
        float4 w = W4[c * 8 + i];
        acc = fmaf(relu_f(p[i].x + q[i].x + b.x), w.x, acc);
        acc = fmaf(relu_f(p[i].y + q[i].y + b.y), w.y, acc);
        acc = fmaf(relu_f(p[i].z + q[i].z + b.z), w.z, acc);
        acc = fmaf(relu_f(p[i].w + q[i].w + b.w), w.w, acc);
    }
    part[(size_t)c * N_CAND + cd] = acc;
}

__global__ void k_sred(const float* __restrict__ part,
                       const float* __restrict__ b2, float* __restrict__ out)
{
    int i = blockIdx.x * 256 + threadIdx.x;
    if (i >= N_CAND) return;
    float s = b2[0];
    #pragma unroll
    for (int c = 0; c < 8; ++c) s += part[(size_t)c * N_CAND + i];
    out[i] = s;
}

// ---------------------------------------------------------------------------
extern "C" void kernel_launch(void* const* d_in, const int* in_sizes, int n_in,
                              void* d_out, int out_size, void* d_ws, size_t ws_size,
                              hipStream_t stream)
{
    const int*   atom_types = (const int*)d_in[0];
    const int*   edge_index = (const int*)d_in[2];
    const int*   candidates = (const int*)d_in[3];
    const float* atom_embed = (const float*)d_in[4];
    const float* atom_W     = (const float*)d_in[5];
    const float* atom_b     = (const float*)d_in[6];
    const float* conv_W     = (const float*)d_in[10];
    const float* conv_b     = (const float*)d_in[11];
    const float* s_W1       = (const float*)d_in[12];
    const float* s_b1       = (const float*)d_in[13];
    const float* s_W2       = (const float*)d_in[14];
    const float* s_b2       = (const float*)d_in[15];
    float* out = (float*)d_out;

    char* w = (char*)d_ws;
    size_t o = 0;
    auto alloc = [&](size_t bytes) {
        void* p = w + o;
        o += (bytes + 255) & ~(size_t)255;
        return p;
    };
    float* h0   = (float*)alloc((size_t)N_NODES * HID * 4);
    float* h1   = (float*)alloc((size_t)N_NODES * HID * 4);
    float* agg  = (float*)alloc((size_t)N_NODES * HID * 4);
    float* ctmp = (float*)alloc((size_t)N_NODES * HID * 4);
    float* E0   = (float*)alloc((size_t)N_ATYPE * HID * 4);
    float* part = (float*)alloc((size_t)8 * N_CAND * 4);
    int*   ints = (int*)alloc((size_t)3 * N_NODES * 4);
    float* ns   = (float*)alloc((size_t)N_NODES * 4);
    float* nd   = (float*)alloc((size_t)N_NODES * 4);
    int*   off  = (int*)alloc((size_t)(N_NODES + 1) * 4);
    int*   csr  = (int*)alloc((size_t)N_EDGES * 4);
    int* dego = ints;
    int* degi = ints + N_NODES;
    int* cur  = ints + 2 * N_NODES;

    hipMemsetAsync(ints, 0, (size_t)3 * N_NODES * 4, stream);

    // E0 = atom_embed @ atom_W + atom_b
    k_gemm<<<dim3(2, 4), 256, 0, stream>>>(atom_embed, atom_W, atom_b, E0, N_ATYPE, 0);

    k_hist<<<(N_EDGES + 255) / 256, 256, 0, stream>>>(edge_index, dego, degi);
    k_norm<<<(N_NODES + 255) / 256, 256, 0, stream>>>(dego, degi, ns, nd);
    k_h0<<<N_NODES / 4, 256, 0, stream>>>(atom_types, E0, ns, h0);
    k_scan<<<1, 1024, 0, stream>>>(degi, off, N_NODES);
    k_fill<<<(N_EDGES + 255) / 256, 256, 0, stream>>>(edge_index, off, cur, csr);

    const float* hc = h0;
    float* hn = h1;
    const int NF4 = N_NODES * 64;
    for (int i = 0; i < N_MP; ++i) {
        k_agg<<<2048, 256, 0, stream>>>(hc, nd, off, csr, agg);
        k_gemm_conv<<<1280, 256, 0, stream>>>(
            agg, conv_W + (size_t)i * HID * HID, hn, ctmp, N_NODES);
        const float* sc = (i < N_MP - 1) ? ns : nullptr;
        k_combine<<<(NF4 + 255) / 256, 256, 0, stream>>>(
            hn, ctmp, conv_b + (size_t)i * HID, sc);
        float* t = (float*)hc; hc = hn; hn = t;
    }
    // After 3 layers: hc == h1. Free: h0 (hn), agg, ctmp.
    float* P = agg;
    float* Q = hn;     // == h0
    k_gemm_pq<<<1280, 256, 0, stream>>>(hc, s_W1, P, Q, N_NODES);

    k_score_part<<<3128, 256, 0, stream>>>(candidates, P, Q, s_b1, s_W2, part);
    k_sred<<<(N_CAND + 255) / 256, 256, 0, stream>>>(part, s_b2, out);
}